// Round 10
// baseline (903.129 us; speedup 1.0000x reference)
//
#include <hip/hip_runtime.h>
#include <math.h>

#define DIM   128
#define NV    (DIM*DIM*DIM)          // elements per volume; 4 volumes
#define SM    1e-6f
#define NITER 40
#define ACC_OFF  96
#define FLAG_OFF 104
#define BUF_OFF  256                 // floats offset into ws for buffers
#define YT 20                        // thread rows: 16 interior + 2 halo each side
#define ZC 8                         // z outputs per block

typedef _Float16 half8 __attribute__((ext_vector_type(8)));

__device__ __forceinline__ float c01(float v){ return fminf(fmaxf(v, 0.f), 1.f); }
__device__ __forceinline__ half8 h8z(){ return (half8)(_Float16)0.f; }

__device__ __forceinline__ _Float16 shflh(_Float16 v, int srcLane){
    unsigned short s = __builtin_bit_cast(unsigned short, v);
    int r = __shfl((int)(unsigned)s, srcLane);
    return __builtin_bit_cast(_Float16, (unsigned short)(r & 0xffff));
}

// 3-point x-sum of an 8-wide fp16 strip, halo via 2 lane shuffles
__device__ __forceinline__ half8 rowsum3(half8 h, int x, int lane){
    _Float16 lft = shflh(h[7], lane - 1); if (x == 0)  lft = (_Float16)0.f;
    _Float16 rgt = shflh(h[0], lane + 1); if (x == 15) rgt = (_Float16)0.f;
    half8 shl, shr;
    shl[0] = lft; shr[7] = rgt;
    #pragma unroll
    for (int k = 1; k < 8; ++k) shl[k] = h[k-1];
    #pragma unroll
    for (int k = 0; k < 7; ++k) shr[k] = h[k+1];
    return shl + h + shr;
}

__device__ __forceinline__ half8 hclip01(half8 v){
    const half8 one  = (half8)(_Float16)1.f;
    const half8 zero = (half8)(_Float16)0.f;
    return __builtin_elementwise_max(__builtin_elementwise_min(v, one), zero);
}

__global__ __launch_bounds__(256)
void k_init_meta(float* meta) { meta[threadIdx.x] = 0.0f; }

__global__ __launch_bounds__(256)
void k_flag(const float4* __restrict__ pred, float* __restrict__ meta, int n4) {
    int stride = gridDim.x * blockDim.x;
    bool hit = false;
    for (int i = blockIdx.x * blockDim.x + threadIdx.x; i < n4; i += stride) {
        float4 p = pred[i];
        hit |= (p.x > 1.f) | (p.y > 1.f) | (p.z > 1.f) | (p.w > 1.f);
    }
    if (hit) meta[FLAG_OFF] = 1.0f;   // same-value racing stores: benign
}

// clip(+optional sigmoid) fp32 inputs -> fp16 buffers. 8 elements/thread.
__global__ __launch_bounds__(256)
void k_prep(const float* __restrict__ pred, const float* __restrict__ tgt,
            const float* __restrict__ meta, _Float16* __restrict__ outP,
            _Float16* __restrict__ outT) {
    const bool sg = (meta[FLAG_OFF] != 0.0f);
    const int idx = blockIdx.x * blockDim.x + threadIdx.x;
    const int i8 = idx * 8;
    float4 a = *(const float4*)(pred + i8);
    float4 b = *(const float4*)(pred + i8 + 4);
    float pv[8] = {a.x,a.y,a.z,a.w,b.x,b.y,b.z,b.w};
    half8 hp, ht;
    #pragma unroll
    for (int k = 0; k < 8; ++k) {
        float p = pv[k];
        if (sg) p = 1.f / (1.f + __expf(-p));
        hp[k] = (_Float16)c01(p);
    }
    *(half8*)(outP + i8) = hp;
    float4 c = *(const float4*)(tgt + i8);
    float4 d = *(const float4*)(tgt + i8 + 4);
    float tv[8] = {c.x,c.y,c.z,c.w,d.x,d.y,d.z,d.w};
    #pragma unroll
    for (int k = 0; k < 8; ++k) ht[k] = (_Float16)c01(tv[k]);
    *(half8*)(outT + i8) = ht;
}

// Fused skeletonize step: packed-fp16 math, 2 planes per barrier, 4-slot LDS
// phase ring, DEPTH-3 post-barrier prefetch queue (pair issued at trip Z is
// consumed at trip Z+6: ~2 compute phases + 2 barriers of lookahead, so the
// vmcnt drain before each s_barrier is of already-landed loads).
__global__ __launch_bounds__(320)
void k_step(const _Float16* __restrict__ src, _Float16* __restrict__ dst,
            float* __restrict__ sums, int iter) {
    __shared__ half8 sA[4][YT][17];
    __shared__ half8 sB[4][YT][17];
    __shared__ float sRed[5];

    const int x    = threadIdx.x;          // 0..15
    const int y    = threadIdx.y;          // 0..19
    const int tid  = y * 16 + x;
    const int lane = tid & 63;
    const int ytile = blockIdx.x & 7;
    const int zch   = blockIdx.x >> 3;     // 0..15
    const int vol   = blockIdx.y;
    const int g     = vol >> 1;
    const int z0    = zch * ZC;
    const int gy    = ytile * 16 - 2 + y;
    const bool rowIn = (gy >= 0) && (gy < DIM);
    const bool midY  = (y >= 1) && (y <= 18);
    const bool outY  = (y >= 2) && (y <= 17);

    // early-stop: all waves run the same 64-lane ballot (no barrier needed)
    bool hitv = (lane < iter) && (sums[lane * 2 + g] < SM);
    const bool done = (__ballot(hitv) != 0ull);

    const _Float16* sp = src + (size_t)vol * NV + (size_t)gy * DIM + x * 8;
    _Float16*       dp = dst + (size_t)vol * NV + (size_t)gy * DIM + x * 8;

    const half8 hz = h8z();
    const half8 inv27v = (half8)(_Float16)(1.f/27.f);
    const half8 smv    = (half8)(_Float16)1e-6f;

    half8 vm4 = hz, vm3 = hz, vm2 = hz, vm1 = hz;
    half8 s1 = hz, s2 = hz;
    half8 r2lo = hz, r2hi = hz;
    half8 g1 = hz, g2 = hz;
    float localSum = 0.f;

    auto LD = [&](int P) -> half8 {
        if (rowIn && P >= 0 && P < DIM && P <= z0 + ZC + 1)
            return *(const half8*)(sp + (size_t)P * (DIM * DIM));
        return h8z();
    };

    // prologue: fill depth-3 queue (cur, +1, +2 pairs)
    half8 cuA = LD(z0 - 2), cuB = LD(z0 - 1);
    half8 n1A = LD(z0),     n1B = LD(z0 + 1);
    half8 n2A = LD(z0 + 2), n2B = LD(z0 + 3);

    for (int Z = z0 - 2; Z <= z0 + ZC + 2; Z += 2) {
        const half8 cA = cuA, cB = cuB;
        cuA = n1A; cuB = n1B;
        n1A = n2A; n1B = n2B;

        const bool liveA = (Z     <= z0 + ZC + 1);
        const bool liveB = (Z + 1 <= z0 + ZC + 1);
        const int sa0 = Z & 3, sa1 = (Z + 1) & 3;
        const int sb0 = (Z - 3) & 3, sb1 = (Z - 2) & 3;

        // ---- pre-barrier: row-sums + ring stores ----
        half8 rsA = hz, rsB = hz;
        if (liveA) { rsA = rowsum3(cA, x, lane); sA[sa0][y][x] = rsA; }
        if (liveB) { rsB = rowsum3(cB, x, lane); sA[sa1][y][x] = rsB; }
        sB[sb0][y][x] = r2lo;
        sB[sb1][y][x] = r2hi;
        __syncthreads();

        // ---- issue tail of the queue now (post-barrier): consumed 3 trips on ----
        n2A = LD(Z + 6); n2B = LD(Z + 7);

        const int ym = (y > 0) ? y - 1 : 0;
        const int yp = (y < YT - 1) ? y + 1 : YT - 1;

        half8 e2lo, e2hi;
        {
            half8 eu = sB[sb0][ym][x], ed = sB[sb0][yp][x];
            e2lo = eu + r2lo + ed;
            half8 fu = sB[sb1][ym][x], fd = sB[sb1][yp][x];
            e2hi = fu + r2hi + fd;
        }

        half8 r2nlo = hz, r2nhi = hz;
        if (liveA) {
            half8 u = sA[sa0][ym][x], d = sA[sa0][yp][x];
            half8 sd = u + rsA + d;
            half8 er = hz;
            if (midY && rowIn && (Z - 1) >= 0 && (Z - 1) < DIM)
                er = hclip01((s2 + s1 + sd) * inv27v - smv);
            s2 = s1; s1 = sd;
            r2nlo = rowsum3(er, x, lane);
        }
        if (liveB) {
            half8 u = sA[sa1][ym][x], d = sA[sa1][yp][x];
            half8 sd = u + rsB + d;
            half8 er = hz;
            if (midY && rowIn && Z >= 0 && Z < DIM)
                er = hclip01((s2 + s1 + sd) * inv27v - smv);
            s2 = s1; s1 = sd;
            r2nhi = rowsum3(er, x, lane);
        }

        const int zoA = Z - 4, zoB = Z - 3;
        if (outY && zoA >= z0) {
            half8 op = hclip01((g2 + g1 + e2lo) * inv27v);
            half8 ho; float part = 0.f;
            #pragma unroll
            for (int k = 0; k < 8; ++k) {
                float nv = (float)vm4[k] * (1.f - (float)op[k] + SM);
                nv = done ? (float)vm4[k] : nv;
                ho[k] = (_Float16)nv;
                part += nv;
            }
            *(half8*)(dp + (size_t)zoA * (DIM * DIM)) = ho;
            localSum += part;
        }
        if (outY && zoB >= z0) {
            half8 op = hclip01((g1 + e2lo + e2hi) * inv27v);
            half8 ho; float part = 0.f;
            #pragma unroll
            for (int k = 0; k < 8; ++k) {
                float nv = (float)vm3[k] * (1.f - (float)op[k] + SM);
                nv = done ? (float)vm3[k] : nv;
                ho[k] = (_Float16)nv;
                part += nv;
            }
            *(half8*)(dp + (size_t)zoB * (DIM * DIM)) = ho;
            localSum += part;
        }

        g2 = e2lo; g1 = e2hi;
        r2lo = r2nlo; r2hi = r2nhi;
        vm4 = vm2; vm3 = vm1; vm2 = cA; vm1 = cB;
    }

    // ---- block reduce localSum -> sums[iter*2+g] ----
    float s = localSum;
    for (int off = 32; off > 0; off >>= 1) s += __shfl_down(s, off);
    if (lane == 0) sRed[tid >> 6] = s;
    __syncthreads();
    if (tid == 0)
        atomicAdd(&sums[iter * 2 + g], sRed[0] + sRed[1] + sRed[2] + sRed[3] + sRed[4]);
}

// XCD-matched dice reduction. grid (64, 8): bx = ytile + 8*zc16 ; by = b + 2*zq
__global__ __launch_bounds__(256)
void k_dice(const _Float16* __restrict__ buf, float* __restrict__ acc) {
    __shared__ float sA[4], sB[4], sC[4];
    const int bx = blockIdx.x, by = blockIdx.y;
    const int ytile = bx & 7, zc16 = bx >> 3;
    const int b = by & 1, zq = by >> 1;
    const int y0 = ytile * 16;
    const int z0 = zc16 * 16 + zq * 4;
    const int tid  = threadIdx.x;
    const int lane = tid & 63;
    const int yy = tid >> 4, xg = tid & 15;

    const _Float16* p = buf + (size_t)b * NV;
    const _Float16* t = buf + (size_t)(2 + b) * NV;

    float si = 0.f, spv = 0.f, stv = 0.f;
    #pragma unroll
    for (int zi = 0; zi < 4; ++zi) {
        const size_t off = ((size_t)(z0 + zi) * DIM + (y0 + yy)) * DIM + xg * 8;
        half8 hp = *(const half8*)(p + off);
        half8 ht = *(const half8*)(t + off);
        #pragma unroll
        for (int k = 0; k < 8; ++k) {
            float pv = (float)hp[k], tv = (float)ht[k];
            si += pv * tv; spv += pv; stv += tv;
        }
    }
    for (int off = 32; off > 0; off >>= 1) {
        si  += __shfl_down(si, off);
        spv += __shfl_down(spv, off);
        stv += __shfl_down(stv, off);
    }
    if (lane == 0) { sA[tid >> 6] = si; sB[tid >> 6] = spv; sC[tid >> 6] = stv; }
    __syncthreads();
    if (tid == 0) {
        atomicAdd(&acc[b * 3 + 0], sA[0] + sA[1] + sA[2] + sA[3]);
        atomicAdd(&acc[b * 3 + 1], sB[0] + sB[1] + sB[2] + sB[3]);
        atomicAdd(&acc[b * 3 + 2], sC[0] + sC[1] + sC[2] + sC[3]);
    }
}

__global__ void k_fin(const float* __restrict__ acc, float* __restrict__ out) {
    float loss = 0.0f;
    for (int b = 0; b < 2; ++b) {
        float inter = acc[b * 3 + 0], spv = acc[b * 3 + 1], stv = acc[b * 3 + 2];
        float dice = (2.0f * inter + SM) / (spv + stv + SM);
        loss += 1.0f - dice;
    }
    out[0] = 0.5f * loss;
}

extern "C" void kernel_launch(void* const* d_in, const int* in_sizes, int n_in,
                              void* d_out, int out_size, void* d_ws, size_t ws_size,
                              hipStream_t stream) {
    (void)in_sizes; (void)n_in; (void)out_size; (void)ws_size;
    const float* pred = (const float*)d_in[0];
    const float* tgt  = (const float*)d_in[1];
    float* out  = (float*)d_out;
    float* meta = (float*)d_ws;
    _Float16* bufA = (_Float16*)(meta + BUF_OFF);
    _Float16* bufB = bufA + (size_t)4 * NV;

    k_init_meta<<<dim3(1), dim3(256), 0, stream>>>(meta);
    k_flag<<<dim3(1024), dim3(256), 0, stream>>>((const float4*)pred, meta, 2 * NV / 4);
    k_prep<<<dim3(2 * NV / 8 / 256), dim3(256), 0, stream>>>(
        pred, tgt, meta, bufA, bufA + (size_t)2 * NV);

    dim3 sgrid(8 * (DIM / ZC), 4);   // (ytile + 8*zch, vol) ; XCD = ytile
    dim3 sblock(16, YT);
    for (int it = 0; it < NITER; ++it) {
        const _Float16* s = (it & 1) ? bufB : bufA;
        _Float16*       d = (it & 1) ? bufA : bufB;
        k_step<<<sgrid, sblock, 0, stream>>>(s, d, meta, it);
    }

    k_dice<<<dim3(64, 8), dim3(256), 0, stream>>>(bufA, meta + ACC_OFF);
    k_fin<<<dim3(1), dim3(1), 0, stream>>>(meta + ACC_OFF, out);
}

// Round 11
// 833.551 us; speedup vs baseline: 1.0835x; 1.0835x over previous
//
#include <hip/hip_runtime.h>
#include <math.h>

#define DIM   128
#define NV    (DIM*DIM*DIM)          // elements per volume; 4 volumes
#define SM    1e-6f
#define NITER 40
#define ACC_OFF  96
#define FLAG_OFF 104
#define BUF_OFF  256                 // floats offset into ws for buffers
#define YT 20                        // thread rows: 16 interior + 2 halo each side
#define ZC 8                         // z outputs per block

typedef _Float16 half8 __attribute__((ext_vector_type(8)));

__device__ __forceinline__ float c01(float v){ return fminf(fmaxf(v, 0.f), 1.f); }
__device__ __forceinline__ half8 h8z(){ return (half8)(_Float16)0.f; }

__device__ __forceinline__ _Float16 shflh(_Float16 v, int srcLane){
    unsigned short s = __builtin_bit_cast(unsigned short, v);
    int r = __shfl((int)(unsigned)s, srcLane);
    return __builtin_bit_cast(_Float16, (unsigned short)(r & 0xffff));
}

// 3-point x-sum of an 8-wide fp16 strip, halo via 2 lane shuffles
__device__ __forceinline__ half8 rowsum3(half8 h, int x, int lane){
    _Float16 lft = shflh(h[7], lane - 1); if (x == 0)  lft = (_Float16)0.f;
    _Float16 rgt = shflh(h[0], lane + 1); if (x == 15) rgt = (_Float16)0.f;
    half8 shl, shr;
    shl[0] = lft; shr[7] = rgt;
    #pragma unroll
    for (int k = 1; k < 8; ++k) shl[k] = h[k-1];
    #pragma unroll
    for (int k = 0; k < 7; ++k) shr[k] = h[k+1];
    return shl + h + shr;
}

__device__ __forceinline__ half8 hclip01(half8 v){
    const half8 one  = (half8)(_Float16)1.f;
    const half8 zero = (half8)(_Float16)0.f;
    return __builtin_elementwise_max(__builtin_elementwise_min(v, one), zero);
}

__global__ __launch_bounds__(256)
void k_init_meta(float* meta) { meta[threadIdx.x] = 0.0f; }

__global__ __launch_bounds__(256)
void k_flag(const float4* __restrict__ pred, float* __restrict__ meta, int n4) {
    int stride = gridDim.x * blockDim.x;
    bool hit = false;
    for (int i = blockIdx.x * blockDim.x + threadIdx.x; i < n4; i += stride) {
        float4 p = pred[i];
        hit |= (p.x > 1.f) | (p.y > 1.f) | (p.z > 1.f) | (p.w > 1.f);
    }
    if (hit) meta[FLAG_OFF] = 1.0f;   // same-value racing stores: benign
}

// clip(+optional sigmoid) fp32 inputs -> fp16 buffers. 8 elements/thread.
__global__ __launch_bounds__(256)
void k_prep(const float* __restrict__ pred, const float* __restrict__ tgt,
            const float* __restrict__ meta, _Float16* __restrict__ outP,
            _Float16* __restrict__ outT) {
    const bool sg = (meta[FLAG_OFF] != 0.0f);
    const int idx = blockIdx.x * blockDim.x + threadIdx.x;
    const int i8 = idx * 8;
    float4 a = *(const float4*)(pred + i8);
    float4 b = *(const float4*)(pred + i8 + 4);
    float pv[8] = {a.x,a.y,a.z,a.w,b.x,b.y,b.z,b.w};
    half8 hp, ht;
    #pragma unroll
    for (int k = 0; k < 8; ++k) {
        float p = pv[k];
        if (sg) p = 1.f / (1.f + __expf(-p));
        hp[k] = (_Float16)c01(p);
    }
    *(half8*)(outP + i8) = hp;
    float4 c = *(const float4*)(tgt + i8);
    float4 d = *(const float4*)(tgt + i8 + 4);
    float tv[8] = {c.x,c.y,c.z,c.w,d.x,d.y,d.z,d.w};
    #pragma unroll
    for (int k = 0; k < 8; ++k) ht[k] = (_Float16)c01(tv[k]);
    *(half8*)(outT + i8) = ht;
}

// Fused skeletonize step: packed-fp16 throughout (incl. emit), 2 planes per
// barrier, 4-slot LDS phase ring, depth-1 POST-barrier prefetch (r9 best).
__global__ __launch_bounds__(320)
void k_step(const _Float16* __restrict__ src, _Float16* __restrict__ dst,
            float* __restrict__ sums, int iter) {
    __shared__ half8 sA[4][YT][17];
    __shared__ half8 sB[4][YT][17];
    __shared__ float sRed[5];

    const int x    = threadIdx.x;          // 0..15
    const int y    = threadIdx.y;          // 0..19
    const int tid  = y * 16 + x;
    const int lane = tid & 63;
    const int ytile = blockIdx.x & 7;
    const int zch   = blockIdx.x >> 3;     // 0..15
    const int vol   = blockIdx.y;
    const int g     = vol >> 1;
    const int z0    = zch * ZC;
    const int gy    = ytile * 16 - 2 + y;
    const bool rowIn = (gy >= 0) && (gy < DIM);
    const bool midY  = (y >= 1) && (y <= 18);
    const bool outY  = (y >= 2) && (y <= 17);

    // early-stop: all waves run the same 64-lane ballot (no barrier needed)
    bool hitv = (lane < iter) && (sums[lane * 2 + g] < SM);
    const bool done = (__ballot(hitv) != 0ull);

    const _Float16* sp = src + (size_t)vol * NV + (size_t)gy * DIM + x * 8;
    _Float16*       dp = dst + (size_t)vol * NV + (size_t)gy * DIM + x * 8;

    const half8 hz = h8z();
    const half8 onev   = (half8)(_Float16)1.f;
    const half8 inv27v = (half8)(_Float16)(1.f/27.f);
    const half8 smv    = (half8)(_Float16)1e-6f;

    half8 vm4 = hz, vm3 = hz, vm2 = hz, vm1 = hz;
    half8 s1 = hz, s2 = hz;
    half8 r2lo = hz, r2hi = hz;
    half8 g1 = hz, g2 = hz;
    float localSum = 0.f;

    auto LD = [&](int P) -> half8 {
        if (rowIn && P >= 0 && P < DIM && P <= z0 + ZC + 1)
            return *(const half8*)(sp + (size_t)P * (DIM * DIM));
        return h8z();
    };

    // fp16 tree-reduce of a half8, accumulated into fp32
    auto SUM8 = [&](half8 t) -> float {
        _Float16 s01 = t[0] + t[1], s23 = t[2] + t[3];
        _Float16 s45 = t[4] + t[5], s67 = t[6] + t[7];
        return (float)((s01 + s23) + (s45 + s67));
    };

    // prologue: first pair only (depth-1 queue)
    half8 hvA = LD(z0 - 2), hvB = LD(z0 - 1);

    for (int Z = z0 - 2; Z <= z0 + ZC + 2; Z += 2) {
        const half8 cA = hvA, cB = hvB;

        const bool liveA = (Z     <= z0 + ZC + 1);
        const bool liveB = (Z + 1 <= z0 + ZC + 1);
        const int sa0 = Z & 3, sa1 = (Z + 1) & 3;
        const int sb0 = (Z - 3) & 3, sb1 = (Z - 2) & 3;

        // ---- pre-barrier: row-sums + ring stores ----
        half8 rsA = hz, rsB = hz;
        if (liveA) { rsA = rowsum3(cA, x, lane); sA[sa0][y][x] = rsA; }
        if (liveB) { rsB = rowsum3(cB, x, lane); sA[sa1][y][x] = rsB; }
        sB[sb0][y][x] = r2lo;
        sB[sb1][y][x] = r2hi;
        __syncthreads();

        // ---- issue next-pair loads post-barrier (proven r9 placement) ----
        hvA = LD(Z + 2); hvB = LD(Z + 3);

        const int ym = (y > 0) ? y - 1 : 0;
        const int yp = (y < YT - 1) ? y + 1 : YT - 1;

        half8 e2lo, e2hi;
        {
            half8 eu = sB[sb0][ym][x], ed = sB[sb0][yp][x];
            e2lo = eu + r2lo + ed;
            half8 fu = sB[sb1][ym][x], fd = sB[sb1][yp][x];
            e2hi = fu + r2hi + fd;
        }

        half8 r2nlo = hz, r2nhi = hz;
        if (liveA) {
            half8 u = sA[sa0][ym][x], d = sA[sa0][yp][x];
            half8 sd = u + rsA + d;
            half8 er = hz;
            if (midY && rowIn && (Z - 1) >= 0 && (Z - 1) < DIM)
                er = hclip01((s2 + s1 + sd) * inv27v - smv);
            s2 = s1; s1 = sd;
            r2nlo = rowsum3(er, x, lane);
        }
        if (liveB) {
            half8 u = sA[sa1][ym][x], d = sA[sa1][yp][x];
            half8 sd = u + rsB + d;
            half8 er = hz;
            if (midY && rowIn && Z >= 0 && Z < DIM)
                er = hclip01((s2 + s1 + sd) * inv27v - smv);
            s2 = s1; s1 = sd;
            r2nhi = rowsum3(er, x, lane);
        }

        // ---- packed-fp16 emit (op >= 0 by construction: min-clamp only) ----
        const int zoA = Z - 4, zoB = Z - 3;
        if (outY && zoA >= z0) {
            half8 op = __builtin_elementwise_min((g2 + g1 + e2lo) * inv27v, onev);
            half8 nv = done ? vm4 : (half8)(vm4 * (onev - op));
            *(half8*)(dp + (size_t)zoA * (DIM * DIM)) = nv;
            localSum += SUM8(nv);
        }
        if (outY && zoB >= z0) {
            half8 op = __builtin_elementwise_min((g1 + e2lo + e2hi) * inv27v, onev);
            half8 nv = done ? vm3 : (half8)(vm3 * (onev - op));
            *(half8*)(dp + (size_t)zoB * (DIM * DIM)) = nv;
            localSum += SUM8(nv);
        }

        g2 = e2lo; g1 = e2hi;
        r2lo = r2nlo; r2hi = r2nhi;
        vm4 = vm2; vm3 = vm1; vm2 = cA; vm1 = cB;
    }

    // ---- block reduce localSum -> sums[iter*2+g] ----
    float s = localSum;
    for (int off = 32; off > 0; off >>= 1) s += __shfl_down(s, off);
    if (lane == 0) sRed[tid >> 6] = s;
    __syncthreads();
    if (tid == 0)
        atomicAdd(&sums[iter * 2 + g], sRed[0] + sRed[1] + sRed[2] + sRed[3] + sRed[4]);
}

// XCD-matched dice reduction. grid (64, 8): bx = ytile + 8*zc16 ; by = b + 2*zq
__global__ __launch_bounds__(256)
void k_dice(const _Float16* __restrict__ buf, float* __restrict__ acc) {
    __shared__ float sA[4], sB[4], sC[4];
    const int bx = blockIdx.x, by = blockIdx.y;
    const int ytile = bx & 7, zc16 = bx >> 3;
    const int b = by & 1, zq = by >> 1;
    const int y0 = ytile * 16;
    const int z0 = zc16 * 16 + zq * 4;
    const int tid  = threadIdx.x;
    const int lane = tid & 63;
    const int yy = tid >> 4, xg = tid & 15;

    const _Float16* p = buf + (size_t)b * NV;
    const _Float16* t = buf + (size_t)(2 + b) * NV;

    float si = 0.f, spv = 0.f, stv = 0.f;
    #pragma unroll
    for (int zi = 0; zi < 4; ++zi) {
        const size_t off = ((size_t)(z0 + zi) * DIM + (y0 + yy)) * DIM + xg * 8;
        half8 hp = *(const half8*)(p + off);
        half8 ht = *(const half8*)(t + off);
        #pragma unroll
        for (int k = 0; k < 8; ++k) {
            float pv = (float)hp[k], tv = (float)ht[k];
            si += pv * tv; spv += pv; stv += tv;
        }
    }
    for (int off = 32; off > 0; off >>= 1) {
        si  += __shfl_down(si, off);
        spv += __shfl_down(spv, off);
        stv += __shfl_down(stv, off);
    }
    if (lane == 0) { sA[tid >> 6] = si; sB[tid >> 6] = spv; sC[tid >> 6] = stv; }
    __syncthreads();
    if (tid == 0) {
        atomicAdd(&acc[b * 3 + 0], sA[0] + sA[1] + sA[2] + sA[3]);
        atomicAdd(&acc[b * 3 + 1], sB[0] + sB[1] + sB[2] + sB[3]);
        atomicAdd(&acc[b * 3 + 2], sC[0] + sC[1] + sC[2] + sC[3]);
    }
}

__global__ void k_fin(const float* __restrict__ acc, float* __restrict__ out) {
    float loss = 0.0f;
    for (int b = 0; b < 2; ++b) {
        float inter = acc[b * 3 + 0], spv = acc[b * 3 + 1], stv = acc[b * 3 + 2];
        float dice = (2.0f * inter + SM) / (spv + stv + SM);
        loss += 1.0f - dice;
    }
    out[0] = 0.5f * loss;
}

extern "C" void kernel_launch(void* const* d_in, const int* in_sizes, int n_in,
                              void* d_out, int out_size, void* d_ws, size_t ws_size,
                              hipStream_t stream) {
    (void)in_sizes; (void)n_in; (void)out_size; (void)ws_size;
    const float* pred = (const float*)d_in[0];
    const float* tgt  = (const float*)d_in[1];
    float* out  = (float*)d_out;
    float* meta = (float*)d_ws;
    _Float16* bufA = (_Float16*)(meta + BUF_OFF);
    _Float16* bufB = bufA + (size_t)4 * NV;

    k_init_meta<<<dim3(1), dim3(256), 0, stream>>>(meta);
    k_flag<<<dim3(1024), dim3(256), 0, stream>>>((const float4*)pred, meta, 2 * NV / 4);
    k_prep<<<dim3(2 * NV / 8 / 256), dim3(256), 0, stream>>>(
        pred, tgt, meta, bufA, bufA + (size_t)2 * NV);

    dim3 sgrid(8 * (DIM / ZC), 4);   // (ytile + 8*zch, vol) ; XCD = ytile
    dim3 sblock(16, YT);
    for (int it = 0; it < NITER; ++it) {
        const _Float16* s = (it & 1) ? bufB : bufA;
        _Float16*       d = (it & 1) ? bufA : bufB;
        k_step<<<sgrid, sblock, 0, stream>>>(s, d, meta, it);
    }

    k_dice<<<dim3(64, 8), dim3(256), 0, stream>>>(bufA, meta + ACC_OFF);
    k_fin<<<dim3(1), dim3(1), 0, stream>>>(meta + ACC_OFF, out);
}